// Round 16
// baseline (1687.291 us; speedup 1.0000x reference)
//
#include <hip/hip_runtime.h>

// HigherOrderGINLayer — round 16: SpMM fused into the residual MLPs (agg goes
// straight to the LDS A-tile as fp16 — no global round-trip; residual
// snatched from LDS into registers before the H overwrite), and 4-edge-per-
// thread ILP for the latency-bound scatter/count. Numerics identical (0.0605).

#define DO 256

typedef unsigned short u16;
typedef _Float16 f16;
typedef __attribute__((ext_vector_type(8))) _Float16 f16x8;
typedef __attribute__((ext_vector_type(4))) _Float16 f16x4;
typedef __attribute__((ext_vector_type(4))) float f32x4;

// Packed weight layout (per 256x256 weight): idx = ((frag*8+ks)*64+lane)*8+e
//   col c = frag*16+(lane&15), k = ks*32+(lane>>4)*8+e

struct WDesc { const float* src; f16* dst; };
struct WPack { WDesc w[13]; };
struct CsrSrc { const int* rows[4]; const int* cols[4]; const float* vals[4]; int E[4]; };

// ------------- prep: count4 (ILP4) ∥ weight transpose ∥ build_P ∥ build_pb -
__global__ __launch_bounds__(256) void prep_kernel(
    CsrSrc cs, int* __restrict__ cnt, int NPo, WPack wp,
    const float* __restrict__ qW, const float* __restrict__ kW,
    const float* __restrict__ qb, f16* __restrict__ pdst, float* __restrict__ pb)
{
    int y = blockIdx.y;
    if (y < 4) {                       // count, 4 edges/thread
        int base = blockIdx.x * 1024 + threadIdx.x;
        #pragma unroll
        for (int k = 0; k < 4; ++k) {
            int e = base + k * 256;
            if (e < cs.E[y]) atomicAdd(&cnt[(size_t)y * NPo + cs.rows[y][e]], 1);
        }
        return;
    }
    if (y < 17) {                      // transpose+pack weight y-4
        if (blockIdx.x >= 256) return;
        WDesc d = wp.w[y - 4];
        int idx = blockIdx.x * 256 + threadIdx.x;
        int e  = idx & 7;
        int l  = (idx >> 3) & 63;
        int ks = (idx >> 9) & 7;
        int f  = idx >> 12;
        int c  = (f << 4) | (l & 15);
        int k  = ks * 32 + ((l >> 4) << 3) + e;
        d.dst[idx] = (f16)d.src[k * 256 + c];
        return;
    }
    if (y == 17) {                     // P = qW @ kW^T, packed
        if (blockIdx.x >= 256) return;
        int idx = blockIdx.x * 256 + threadIdx.x;
        int e  = idx & 7;
        int l  = (idx >> 3) & 63;
        int ks = (idx >> 9) & 7;
        int f  = idx >> 12;
        int c  = (f << 4) | (l & 15);
        int k  = ks * 32 + ((l >> 4) << 3) + e;
        float s = 0.f;
        #pragma unroll 8
        for (int p = 0; p < 128; ++p) s += qW[k * 128 + p] * kW[c * 128 + p];
        pdst[idx] = (f16)s;
        return;
    }
    if (blockIdx.x != 0) return;       // y == 18: pb
    int c = threadIdx.x;
    float s = 0.f;
    #pragma unroll 8
    for (int p = 0; p < 128; ++p) s += qb[p] * kW[c * 128 + p];
    pb[c] = s;
}

__global__ __launch_bounds__(1024) void scan4_kernel(
    const int* __restrict__ cnt0, int* __restrict__ off0, int N, int NPo)
{
    const int* cnt = cnt0 + (size_t)blockIdx.x * NPo;
    int* off = off0 + (size_t)blockIdx.x * NPo;
    __shared__ int part[1024];
    const int t = threadIdx.x;
    const int chunk = (N + 1023) / 1024;
    const int lo = t * chunk;
    const int hi = min(lo + chunk, N);
    int s = 0;
    for (int i = lo; i < hi; ++i) s += cnt[i];
    part[t] = s;
    __syncthreads();
    for (int d = 1; d < 1024; d <<= 1) {
        int u = (t >= d) ? part[t - d] : 0;
        __syncthreads();
        part[t] += u;
        __syncthreads();
    }
    int running = part[t] - s;
    for (int i = lo; i < hi; ++i) { off[i] = running; running += cnt[i]; }
    if (t == 1023) off[N] = part[1023];
}

// ------------- shared GEMM device pieces -----------------------------------
static __device__ __forceinline__ void stage_A(
    char* smem, const f16* A, const float* A32, int brow, int N, int tid)
{
    #pragma unroll
    for (int j = 0; j < 8; ++j) {
        int i = tid + j * 256;
        int row = i >> 5, slot = i & 31;
        int srow = brow + row; srow = srow < N ? srow : N - 1;
        f16x8 v;
        if (A32) {
            const float* s = &A32[(size_t)srow * 256 + slot * 8];
            float4 v0 = *(const float4*)s;
            float4 v1 = *(const float4*)(s + 4);
            v = f16x8{(f16)v0.x, (f16)v0.y, (f16)v0.z, (f16)v0.w,
                      (f16)v1.x, (f16)v1.y, (f16)v1.z, (f16)v1.w};
        } else {
            v = *(const f16x8*)&A[(size_t)srow * 256 + slot * 8];
        }
        int db = (row * 512 + slot * 16) ^ ((row & 7) << 4);
        *(f16x8*)(smem + db) = v;
    }
}

static __device__ __forceinline__ void gemm_from_lds(
    const char* smem, const f16* W, f32x4 (&acc)[4][4],
    int wave, int lane, int lrow, int kg)
{
    #pragma unroll
    for (int ks = 0; ks < 8; ++ks) {
        f16x8 ah[4], bh[4];
        #pragma unroll
        for (int m = 0; m < 4; ++m) {
            int ab = ((m * 16 + lrow) * 512 + (ks * 4 + kg) * 16) ^ ((lrow & 7) << 4);
            ah[m] = *(const f16x8*)(smem + ab);
        }
        #pragma unroll
        for (int n = 0; n < 4; ++n)
            bh[n] = *(const f16x8*)&W[(size_t)(((wave * 4 + n) * 8 + ks) << 9) + (lane << 3)];
        #pragma unroll
        for (int m = 0; m < 4; ++m)
            #pragma unroll
            for (int n = 0; n < 4; ++n)
                acc[m][n] = __builtin_amdgcn_mfma_f32_16x16x32_f16(
                                ah[m], bh[n], acc[m][n], 0, 0, 0);
    }
}

// GEMM1+relu -> H(LDS, overwrites A region) -> GEMM2; A already staged.
static __device__ __forceinline__ void mlp_from_lds(
    char* smem, const f16* W1, const float* b1, const f16* W2,
    f32x4 (&acc)[4][4], int wave, int lane, int lrow, int kg)
{
    const int wc = wave * 64;
    gemm_from_lds(smem, W1, acc, wave, lane, lrow, kg);
    __syncthreads();
    #pragma unroll
    for (int n = 0; n < 4; ++n) {
        int c = wc + n * 16 + lrow;
        float bv = b1[c];
        #pragma unroll
        for (int m = 0; m < 4; ++m)
            #pragma unroll
            for (int j = 0; j < 4; ++j) {
                int rl = m * 16 + kg * 4 + j;
                float v = fmaxf(acc[m][n][j] + bv, 0.f);
                int hb = (rl * 512 + c * 2) ^ ((rl & 7) << 4);
                *(f16*)(smem + hb) = (f16)v;
            }
    }
    __syncthreads();
    #pragma unroll
    for (int m = 0; m < 4; ++m)
        #pragma unroll
        for (int n = 0; n < 4; ++n)
            acc[m][n] = f32x4{0.f, 0.f, 0.f, 0.f};
    gemm_from_lds(smem, W2, acc, wave, lane, lrow, kg);
}

static __device__ __forceinline__ void fused_mlp_body(
    char* smem, const f16* A, const float* A32,
    const f16* W1, const float* b1, const f16* W2, const float* b2,
    const f16* Ad, f16* Ch, float* Cf, int N, int brow)
{
    const int tid  = threadIdx.x;
    const int wave = tid >> 6, lane = tid & 63;
    const int lrow = lane & 15, kg = lane >> 4;
    const int wc   = wave * 64;

    stage_A(smem, A, A32, brow, N, tid);
    __syncthreads();

    f32x4 acc[4][4] = {};
    mlp_from_lds(smem, W1, b1, W2, acc, wave, lane, lrow, kg);

    #pragma unroll
    for (int n = 0; n < 4; ++n) {
        int c = wc + n * 16 + lrow;
        float bv = b2[c];
        #pragma unroll
        for (int m = 0; m < 4; ++m)
            #pragma unroll
            for (int j = 0; j < 4; ++j) {
                int r = brow + m * 16 + kg * 4 + j;
                if (r >= N) continue;
                size_t o = (size_t)r * 256 + c;
                float v = acc[m][n][j] + bv;
                if (Ad) v += (float)Ad[o];
                if (Cf) Cf[o] = v;
                else    Ch[o] = (f16)v;
            }
    }
}

static __device__ __forceinline__ void gemm1_body(
    char* smem, const float* A32, const f16* W1, const float* b1,
    f16* Ch, int N, int brow)
{
    const int tid  = threadIdx.x;
    const int wave = tid >> 6, lane = tid & 63;
    const int lrow = lane & 15, kg = lane >> 4;
    const int wc   = wave * 64;

    stage_A(smem, nullptr, A32, brow, N, tid);
    __syncthreads();
    f32x4 acc[4][4] = {};
    gemm_from_lds(smem, W1, acc, wave, lane, lrow, kg);

    #pragma unroll
    for (int n = 0; n < 4; ++n) {
        int c = wc + n * 16 + lrow;
        float bv = b1[c];
        #pragma unroll
        for (int m = 0; m < 4; ++m)
            #pragma unroll
            for (int j = 0; j < 4; ++j) {
                int r = brow + m * 16 + kg * 4 + j;
                if (r >= N) continue;
                Ch[(size_t)r * 256 + c] = (f16)(acc[m][n][j] + bv);
            }
    }
}

// ------------- stage2: scatter4 (ILP4) ∥ ft-GEMM ∥ em-MLP ------------------
__global__ __launch_bounds__(256) void stage2_kernel(
    CsrSrc cs, const int* __restrict__ off, int* __restrict__ cur,
    int2* __restrict__ se, int NPo, int Emax,
    const float* __restrict__ features, const float* __restrict__ edge_features,
    const f16* __restrict__ w_ft, const float* __restrict__ ft_b,
    const f16* __restrict__ w_em1, const float* __restrict__ em_b1,
    const f16* __restrict__ w_em2, const float* __restrict__ em_b2,
    f16* __restrict__ F, f16* __restrict__ ef, int N)
{
    __shared__ char smem[32768];
    int y = blockIdx.y;
    if (y < 4) {                       // scatter, 4 edges/thread
        int base = blockIdx.x * 1024 + threadIdx.x;
        #pragma unroll
        for (int k = 0; k < 4; ++k) {
            int e = base + k * 256;
            if (e < cs.E[y]) {
                int r = cs.rows[y][e];
                int p = off[(size_t)y * NPo + r] + atomicAdd(&cur[(size_t)y * NPo + r], 1);
                se[(size_t)y * Emax + p] = make_int2(cs.cols[y][e],
                                                     __float_as_int(cs.vals[y][e]));
            }
        }
        return;
    }
    int gx = blockIdx.x;
    if (gx >= (N + 63) / 64) return;
    if (y == 4)
        gemm1_body(smem, features, w_ft, ft_b, F, N, gx * 64);
    else
        fused_mlp_body(smem, nullptr, edge_features, w_em1, em_b1, w_em2, em_b2,
                       nullptr, ef, nullptr, N, gx * 64);
}

// ------------- fused SpMM + residual MLP (fo/so/to/qo) ---------------------
// Block = (row-block, y): waves gather their 16 rows' edges; agg -> LDS f16
// (same rounding as the old global round-trip). y=0: dual gather, aggef ->
// global scratch (same-block, reread at epilogue). y>=1: residual snatched
// from LDS into registers after GEMM1 (before H overwrites the A region).
struct SpmmMlp4 {
    const int* off; const int2* se; int NPo; int Emax;
    const f16* F; const f16* ef;
    f16* aggef;                        // scratch for y=0 residual
    const f16* w1[4]; const f16* w2[4];
    const float* b1[4]; const float* b2[4];
    f16* out[4];
};
__global__ __launch_bounds__(256) void spmm_mlp4_kernel(SpmmMlp4 p, int N) {
    __shared__ char smem[32768];
    const int y = blockIdx.y;
    const int brow = blockIdx.x * 64;
    const int tid  = threadIdx.x;
    const int wave = tid >> 6, lane = tid & 63;
    const int lrow = lane & 15, kg = lane >> 4;
    const int wc   = wave * 64;

    const int* off = p.off + (size_t)y * p.NPo;
    const int2* se = p.se + (size_t)y * p.Emax;

    // ---- spmm phase: wave handles rows brow + wave*16 + {0..15} ----
    for (int rr = 0; rr < 16; ++rr) {
        int rl = wave * 16 + rr;
        int r  = brow + rl;
        float a0 = 0.f, a1 = 0.f, a2 = 0.f, a3 = 0.f;
        float c0 = 0.f, c1 = 0.f, c2 = 0.f, c3 = 0.f;
        if (r < N) {
            int e0 = off[r], e1 = off[r + 1];
            if (y == 0) {              // dual: agg1 (F) + aggef (ef)
                int e = e0;
                for (; e + 1 < e1; e += 2) {
                    int2 ev0 = se[e], ev1 = se[e + 1];
                    float v0 = __int_as_float(ev0.y), v1 = __int_as_float(ev1.y);
                    size_t x0o = (size_t)ev0.x * DO + lane * 4;
                    size_t x1o = (size_t)ev1.x * DO + lane * 4;
                    f16x4 f0 = *(const f16x4*)&p.F[x0o];
                    f16x4 g0 = *(const f16x4*)&p.ef[x0o];
                    f16x4 f1 = *(const f16x4*)&p.F[x1o];
                    f16x4 g1 = *(const f16x4*)&p.ef[x1o];
                    a0 = fmaf(v0, (float)f0[0], a0); a1 = fmaf(v0, (float)f0[1], a1);
                    a2 = fmaf(v0, (float)f0[2], a2); a3 = fmaf(v0, (float)f0[3], a3);
                    c0 = fmaf(v0, (float)g0[0], c0); c1 = fmaf(v0, (float)g0[1], c1);
                    c2 = fmaf(v0, (float)g0[2], c2); c3 = fmaf(v0, (float)g0[3], c3);
                    a0 = fmaf(v1, (float)f1[0], a0); a1 = fmaf(v1, (float)f1[1], a1);
                    a2 = fmaf(v1, (float)f1[2], a2); a3 = fmaf(v1, (float)f1[3], a3);
                    c0 = fmaf(v1, (float)g1[0], c0); c1 = fmaf(v1, (float)g1[1], c1);
                    c2 = fmaf(v1, (float)g1[2], c2); c3 = fmaf(v1, (float)g1[3], c3);
                }
                if (e < e1) {
                    int2 ev = se[e];
                    float v = __int_as_float(ev.y);
                    size_t xo = (size_t)ev.x * DO + lane * 4;
                    f16x4 f0 = *(const f16x4*)&p.F[xo];
                    f16x4 g0 = *(const f16x4*)&p.ef[xo];
                    a0 = fmaf(v, (float)f0[0], a0); a1 = fmaf(v, (float)f0[1], a1);
                    a2 = fmaf(v, (float)f0[2], a2); a3 = fmaf(v, (float)f0[3], a3);
                    c0 = fmaf(v, (float)g0[0], c0); c1 = fmaf(v, (float)g0[1], c1);
                    c2 = fmaf(v, (float)g0[2], c2); c3 = fmaf(v, (float)g0[3], c3);
                }
            } else {                   // single, 4-way unroll
                int e = e0;
                for (; e + 3 < e1; e += 4) {
                    int2 ev0 = se[e], ev1 = se[e + 1], ev2 = se[e + 2], ev3 = se[e + 3];
                    f16x4 x0 = *(const f16x4*)&p.F[(size_t)ev0.x * DO + lane * 4];
                    f16x4 x1 = *(const f16x4*)&p.F[(size_t)ev1.x * DO + lane * 4];
                    f16x4 x2 = *(const f16x4*)&p.F[(size_t)ev2.x * DO + lane * 4];
                    f16x4 x3 = *(const f16x4*)&p.F[(size_t)ev3.x * DO + lane * 4];
                    float v0 = __int_as_float(ev0.y), v1 = __int_as_float(ev1.y);
                    float v2 = __int_as_float(ev2.y), v3 = __int_as_float(ev3.y);
                    a0 = fmaf(v0, (float)x0[0], a0); a1 = fmaf(v0, (float)x0[1], a1);
                    a2 = fmaf(v0, (float)x0[2], a2); a3 = fmaf(v0, (float)x0[3], a3);
                    a0 = fmaf(v1, (float)x1[0], a0); a1 = fmaf(v1, (float)x1[1], a1);
                    a2 = fmaf(v1, (float)x1[2], a2); a3 = fmaf(v1, (float)x1[3], a3);
                    a0 = fmaf(v2, (float)x2[0], a0); a1 = fmaf(v2, (float)x2[1], a1);
                    a2 = fmaf(v2, (float)x2[2], a2); a3 = fmaf(v2, (float)x2[3], a3);
                    a0 = fmaf(v3, (float)x3[0], a0); a1 = fmaf(v3, (float)x3[1], a1);
                    a2 = fmaf(v3, (float)x3[2], a2); a3 = fmaf(v3, (float)x3[3], a3);
                }
                for (; e < e1; ++e) {
                    int2 ev = se[e];
                    float v = __int_as_float(ev.y);
                    f16x4 x = *(const f16x4*)&p.F[(size_t)ev.x * DO + lane * 4];
                    a0 = fmaf(v, (float)x[0], a0); a1 = fmaf(v, (float)x[1], a1);
                    a2 = fmaf(v, (float)x[2], a2); a3 = fmaf(v, (float)x[3], a3);
                }
            }
        }
        // agg -> LDS (fp16, swizzled): 8B per lane
        int addr = ((rl * 512 + (lane >> 1) * 16) ^ ((rl & 7) << 4)) + (lane & 1) * 8;
        f16x4 o = {(f16)a0, (f16)a1, (f16)a2, (f16)a3};
        *(f16x4*)(smem + addr) = o;
        if (y == 0 && r < N) {         // aggef -> global scratch (same block)
            f16x4 og = {(f16)c0, (f16)c1, (f16)c2, (f16)c3};
            *(f16x4*)&p.aggef[(size_t)r * 256 + lane * 4] = og;
        }
    }
    __syncthreads();

    // ---- GEMM1 ----
    f32x4 acc[4][4] = {};
    gemm_from_lds(smem, p.w1[y], acc, wave, lane, lrow, kg);

    // ---- residual snatch (y>=1): read own epilogue agg values from LDS ----
    f16x4 res[4][4];                   // [m][n], element j
    if (y >= 1) {
        #pragma unroll
        for (int m = 0; m < 4; ++m)
            #pragma unroll
            for (int n = 0; n < 4; ++n) {
                int c = wc + n * 16 + lrow;
                #pragma unroll
                for (int j = 0; j < 4; ++j) {
                    int rl2 = m * 16 + kg * 4 + j;
                    int ab = (rl2 * 512 + c * 2) ^ ((rl2 & 7) << 4);
                    res[m][n][j] = *(const f16*)(smem + ab);
                }
            }
    }
    __syncthreads();

    // ---- H = relu(acc + b1) -> LDS (overwrites A region) ----
    const float* b1 = p.b1[y];
    #pragma unroll
    for (int n = 0; n < 4; ++n) {
        int c = wc + n * 16 + lrow;
        float bv = b1[c];
        #pragma unroll
        for (int m = 0; m < 4; ++m)
            #pragma unroll
            for (int j = 0; j < 4; ++j) {
                int rl2 = m * 16 + kg * 4 + j;
                float v = fmaxf(acc[m][n][j] + bv, 0.f);
                int hb = (rl2 * 512 + c * 2) ^ ((rl2 & 7) << 4);
                *(f16*)(smem + hb) = (f16)v;
            }
    }
    __syncthreads();

    // ---- GEMM2 ----
    #pragma unroll
    for (int m = 0; m < 4; ++m)
        #pragma unroll
        for (int n = 0; n < 4; ++n)
            acc[m][n] = f32x4{0.f, 0.f, 0.f, 0.f};
    gemm_from_lds(smem, p.w2[y], acc, wave, lane, lrow, kg);

    // ---- epilogue: + b2 + residual -> out (fp16) ----
    const float* b2 = p.b2[y];
    f16* out = p.out[y];
    #pragma unroll
    for (int n = 0; n < 4; ++n) {
        int c = wc + n * 16 + lrow;
        float bv = b2[c];
        #pragma unroll
        for (int m = 0; m < 4; ++m)
            #pragma unroll
            for (int j = 0; j < 4; ++j) {
                int r = brow + m * 16 + kg * 4 + j;
                if (r >= N) continue;
                size_t o = (size_t)r * 256 + c;
                float v = acc[m][n][j] + bv;
                if (y == 0) v += (float)p.aggef[o];
                else        v += (float)res[m][n][j];
                out[o] = (f16)v;
            }
    }
}

// ------------- scores + softmax + combine + final MLP ----------------------
__global__ __launch_bounds__(256) void score_combine_mlp_kernel(
    const f16* __restrict__ F, const f16* __restrict__ P,
    const float* __restrict__ pb,
    const f16* __restrict__ F1, const f16* __restrict__ F2,
    const f16* __restrict__ F3, const f16* __restrict__ F4,
    const f16* __restrict__ mW1, const float* __restrict__ mb1,
    const f16* __restrict__ mW2, const float* __restrict__ mb2,
    float* __restrict__ Out, int N)
{
    __shared__ char smem[32768];
    __shared__ float sred[4][64][5];
    __shared__ float w5[64][5];

    const int tid  = threadIdx.x;
    const int wave = tid >> 6, lane = tid & 63;
    const int lrow = lane & 15, kg = lane >> 4;
    const int wc   = wave * 64;
    const int brow = blockIdx.x * 64;

    stage_A(smem, F, nullptr, brow, N, tid);
    __syncthreads();

    f32x4 acc[4][4] = {};
    gemm_from_lds(smem, P, acc, wave, lane, lrow, kg);

    #pragma unroll
    for (int m = 0; m < 4; ++m) {
        #pragma unroll
        for (int j = 0; j < 4; ++j) {
            int rl = m * 16 + kg * 4 + j;
            int r  = brow + rl;
            float p0 = 0.f, p1 = 0.f, p2 = 0.f, p3 = 0.f, p4 = 0.f;
            if (r < N) {
                #pragma unroll
                for (int n = 0; n < 4; ++n) {
                    int c = wc + n * 16 + lrow;
                    float v = acc[m][n][j] + pb[c];
                    int ab = (rl * 512 + c * 2) ^ ((rl & 7) << 4);
                    float f0 = (float)*(const f16*)(smem + ab);
                    size_t fo = (size_t)r * 256 + c;
                    p0 += v * f0;
                    p1 += v * (float)F1[fo];
                    p2 += v * (float)F2[fo];
                    p3 += v * (float)F3[fo];
                    p4 += v * (float)F4[fo];
                }
            }
            #pragma unroll
            for (int d = 1; d < 16; d <<= 1) {
                p0 += __shfl_xor(p0, d, 64);
                p1 += __shfl_xor(p1, d, 64);
                p2 += __shfl_xor(p2, d, 64);
                p3 += __shfl_xor(p3, d, 64);
                p4 += __shfl_xor(p4, d, 64);
            }
            if (lrow == 0) {
                sred[wave][rl][0] = p0; sred[wave][rl][1] = p1;
                sred[wave][rl][2] = p2; sred[wave][rl][3] = p3;
                sred[wave][rl][4] = p4;
            }
        }
    }
    __syncthreads();

    if (tid < 64) {
        float s[5];
        #pragma unroll
        for (int k = 0; k < 5; ++k)
            s[k] = sred[0][tid][k] + sred[1][tid][k] + sred[2][tid][k] + sred[3][tid][k];
        float mx = fmaxf(fmaxf(fmaxf(s[0], s[1]), fmaxf(s[2], s[3])), s[4]);
        float sum = 0.f;
        #pragma unroll
        for (int k = 0; k < 5; ++k) { s[k] = expf(s[k] - mx); sum += s[k]; }
        float inv = 1.f / sum;
        #pragma unroll
        for (int k = 0; k < 5; ++k) w5[tid][k] = s[k] * inv;
    }
    __syncthreads();

    #pragma unroll
    for (int m = 0; m < 4; ++m) {
        #pragma unroll
        for (int j = 0; j < 4; ++j) {
            int rl = m * 16 + kg * 4 + j;
            int r  = brow + rl;
            float w0 = w5[rl][0], w1 = w5[rl][1], w2 = w5[rl][2],
                  w3 = w5[rl][3], w4 = w5[rl][4];
            #pragma unroll
            for (int n = 0; n < 4; ++n) {
                int c = wc + n * 16 + lrow;
                int ab = (rl * 512 + c * 2) ^ ((rl & 7) << 4);
                float f0 = (float)*(const f16*)(smem + ab);
                float res = f0;
                if (r < N) {
                    size_t fo = (size_t)r * 256 + c;
                    res = w0 * f0
                        + w1 * (float)F1[fo]
                        + w2 * (float)F2[fo]
                        + w3 * (float)F3[fo]
                        + w4 * (float)F4[fo];
                }
                *(f16*)(smem + ab) = (f16)res;
            }
        }
    }
    __syncthreads();

    #pragma unroll
    for (int m = 0; m < 4; ++m)
        #pragma unroll
        for (int n = 0; n < 4; ++n)
            acc[m][n] = f32x4{0.f, 0.f, 0.f, 0.f};
    mlp_from_lds(smem, mW1, mb1, mW2, acc, wave, lane, lrow, kg);

    #pragma unroll
    for (int n = 0; n < 4; ++n) {
        int c = wc + n * 16 + lrow;
        float bv = mb2[c];
        #pragma unroll
        for (int m = 0; m < 4; ++m)
            #pragma unroll
            for (int j = 0; j < 4; ++j) {
                int r = brow + m * 16 + kg * 4 + j;
                if (r >= N) continue;
                Out[(size_t)r * 256 + c] = acc[m][n][j] + bv;
            }
    }
}

extern "C" void kernel_launch(void* const* d_in, const int* in_sizes, int n_in,
                              void* d_out, int out_size, void* d_ws, size_t ws_size,
                              hipStream_t stream)
{
    const float* features      = (const float*)d_in[0];
    const float* edge_features = (const float*)d_in[1];
    CsrSrc cs;
    for (int i = 0; i < 4; ++i) {
        const int* idx = (const int*)d_in[2 + 2 * i];
        cs.E[i]    = in_sizes[3 + 2 * i];
        cs.rows[i] = idx;
        cs.cols[i] = idx + cs.E[i];
        cs.vals[i] = (const float*)d_in[3 + 2 * i];
    }
    const int Emax = max(max(cs.E[0], cs.E[1]), max(cs.E[2], cs.E[3]));

    const float* ft_W = (const float*)d_in[10]; const float* ft_b = (const float*)d_in[11];
    const float* fo_W1 = (const float*)d_in[12]; const float* fo_b1 = (const float*)d_in[13];
    const float* fo_W2 = (const float*)d_in[14]; const float* fo_b2 = (const float*)d_in[15];
    const float* em_W1 = (const float*)d_in[16]; const float* em_b1 = (const float*)d_in[17];
    const float* em_W2 = (const float*)d_in[18]; const float* em_b2 = (const float*)d_in[19];
    const float* so_W1 = (const float*)d_in[20]; const float* so_b1 = (const float*)d_in[21];
    const float* so_W2 = (const float*)d_in[22]; const float* so_b2 = (const float*)d_in[23];
    const float* to_W1 = (const float*)d_in[24]; const float* to_b1 = (const float*)d_in[25];
    const float* to_W2 = (const float*)d_in[26]; const float* to_b2 = (const float*)d_in[27];
    const float* qo_W1 = (const float*)d_in[28]; const float* qo_b1 = (const float*)d_in[29];
    const float* qo_W2 = (const float*)d_in[30]; const float* qo_b2 = (const float*)d_in[31];
    const float* m_W1  = (const float*)d_in[32]; const float* m_b1  = (const float*)d_in[33];
    const float* m_W2  = (const float*)d_in[34]; const float* m_b2  = (const float*)d_in[35];
    const float* q_W   = (const float*)d_in[36]; const float* q_b   = (const float*)d_in[37];
    const float* k_W   = (const float*)d_in[38]; const float* k_b   = (const float*)d_in[39];
    (void)k_b;   // q.k_b constant across the 5 scores -> softmax-invariant

    const int N = in_sizes[0] / 256;
    const size_t NS = (size_t)N * DO;

    // ---- workspace: CSR(4, packed) + 7 fp16 slots + packed WT -------------
    char* base = (char*)d_ws;
    size_t o = 0;
    auto take = [&](size_t bytes) { char* p = base + o; o += (bytes + 63) & ~(size_t)63; return p; };
    const int NPo = (N + 64) & ~63;
    int*  cnt = (int*)take((size_t)4 * NPo * 4);
    int*  cur = (int*)take((size_t)4 * NPo * 4);   // contiguous with cnt
    int*  off = (int*)take((size_t)4 * NPo * 4);
    int2* se  = (int2*)take((size_t)4 * Emax * 8);
    f16* B1 = (f16*)take(NS * 2);      // fo
    f16* B2 = (f16*)take(NS * 2);      // aggef scratch
    f16* B3 = (f16*)take(NS * 2);      // ef
    f16* B4 = (f16*)take(NS * 2);      // F
    f16* B5 = (f16*)take(NS * 2);      // so
    f16* B6 = (f16*)take(NS * 2);      // to
    f16* B7 = (f16*)take(NS * 2);      // qo
    const size_t WSQ = 65536;
    f16* WT = (f16*)take(14 * WSQ * 2);    // 13 weights + P (slot 13), packed
    float* pb = (float*)take(256 * 4);
    if (o > ws_size) return;           // graceful guard

    f16* F = B4;

    f16* w[14];
    for (int i = 0; i < 14; ++i) w[i] = WT + (size_t)i * WSQ;

    dim3 blk(256);
    const int EG4 = (Emax + 1023) / 1024;
    const int GG  = (N + 63) / 64;
    const int PX  = (EG4 > 256) ? EG4 : 256;
    const int SX  = (EG4 > GG) ? EG4 : GG;

    // 0. zero cnt+cur (contiguous)
    hipMemsetAsync(cnt, 0, (size_t)8 * NPo * 4, stream);

    // 1. prep: count4(ILP4) ∥ transpose13 ∥ build_P ∥ build_pb
    {
        WPack wp;
        const float* src[13] = {ft_W, fo_W1, fo_W2, em_W1, em_W2, so_W1, so_W2,
                                to_W1, to_W2, qo_W1, qo_W2, m_W1, m_W2};
        for (int i = 0; i < 13; ++i) { wp.w[i].src = src[i]; wp.w[i].dst = w[i]; }
        hipLaunchKernelGGL(prep_kernel, dim3(PX, 19), blk, 0, stream,
                           cs, cnt, NPo, wp, q_W, k_W, q_b, w[13], pb);
    }
    // 2. scan4
    hipLaunchKernelGGL(scan4_kernel, dim3(4), dim3(1024), 0, stream, cnt, off, N, NPo);
    // 3. stage2: scatter4(ILP4) ∥ ft-GEMM ∥ em-MLP
    hipLaunchKernelGGL(stage2_kernel, dim3(SX, 6), blk, 0, stream,
                       cs, off, cur, se, NPo, Emax,
                       features, edge_features,
                       w[0], ft_b, w[3], em_b1, w[4], em_b2, F, B3, N);
    // 4. fused spmm + residual MLPs: fo->B1, so->B5, to->B6, qo->B7
    {
        SpmmMlp4 p;
        p.off = off; p.se = se; p.NPo = NPo; p.Emax = Emax;
        p.F = F; p.ef = B3; p.aggef = B2;
        int wi1[4] = {1, 5, 7, 9}, wi2[4] = {2, 6, 8, 10};
        const float* bb1[4] = {fo_b1, so_b1, to_b1, qo_b1};
        const float* bb2[4] = {fo_b2, so_b2, to_b2, qo_b2};
        f16* out[4] = {B1, B5, B6, B7};
        for (int i = 0; i < 4; ++i) {
            p.w1[i] = w[wi1[i]]; p.w2[i] = w[wi2[i]];
            p.b1[i] = bb1[i]; p.b2[i] = bb2[i]; p.out[i] = out[i];
        }
        hipLaunchKernelGGL(spmm_mlp4_kernel, dim3(GG, 4), blk, 0, stream, p, N);
    }
    // 5. scores + softmax + combine + final MLP -> f32 d_out (write-only)
    hipLaunchKernelGGL(score_combine_mlp_kernel, dim3(GG), blk, 0, stream,
                       F, w[13], pb, B1, B5, B6, B7,
                       w[11], m_b1, w[12], m_b2, (float*)d_out, N);
}

// Round 17
// 1079.591 us; speedup vs baseline: 1.5629x; 1.5629x over previous
//
#include <hip/hip_runtime.h>

// HigherOrderGINLayer — round 17: round-15 structure (best: 1075us) + the two
// safe pieces of round 16: ILP4 count and ILP4 scatter. Round-16's spmm+MLP
// fusion REGRESSED (1687us): each wave walked 16 rows serially -> 5x fewer
// outstanding gather streams at 11% occupancy. Lesson: latency-bound gathers
// need max wave count; keep spmm5 as its own 62.5k-wave dispatch.

#define DO 256

typedef unsigned short u16;
typedef _Float16 f16;
typedef __attribute__((ext_vector_type(8))) _Float16 f16x8;
typedef __attribute__((ext_vector_type(4))) _Float16 f16x4;
typedef __attribute__((ext_vector_type(4))) float f32x4;

// Packed weight layout (per 256x256 weight): idx = ((frag*8+ks)*64+lane)*8+e
//   col c = frag*16+(lane&15), k = ks*32+(lane>>4)*8+e

struct WDesc { const float* src; f16* dst; };
struct WPack { WDesc w[13]; };
struct CsrSrc { const int* rows[4]; const int* cols[4]; const float* vals[4]; int E[4]; };

// ------------- prep: count4 (ILP4) ∥ weight transpose ∥ build_P ∥ build_pb -
__global__ __launch_bounds__(256) void prep_kernel(
    CsrSrc cs, int* __restrict__ cnt, int NPo, WPack wp,
    const float* __restrict__ qW, const float* __restrict__ kW,
    const float* __restrict__ qb, f16* __restrict__ pdst, float* __restrict__ pb)
{
    int y = blockIdx.y;
    if (y < 4) {                       // count, 4 edges/thread
        int base = blockIdx.x * 1024 + threadIdx.x;
        #pragma unroll
        for (int k = 0; k < 4; ++k) {
            int e = base + k * 256;
            if (e < cs.E[y]) atomicAdd(&cnt[(size_t)y * NPo + cs.rows[y][e]], 1);
        }
        return;
    }
    if (y < 17) {                      // transpose+pack weight y-4
        if (blockIdx.x >= 256) return;
        WDesc d = wp.w[y - 4];
        int idx = blockIdx.x * 256 + threadIdx.x;
        int e  = idx & 7;
        int l  = (idx >> 3) & 63;
        int ks = (idx >> 9) & 7;
        int f  = idx >> 12;
        int c  = (f << 4) | (l & 15);
        int k  = ks * 32 + ((l >> 4) << 3) + e;
        d.dst[idx] = (f16)d.src[k * 256 + c];
        return;
    }
    if (y == 17) {                     // P = qW @ kW^T, packed
        if (blockIdx.x >= 256) return;
        int idx = blockIdx.x * 256 + threadIdx.x;
        int e  = idx & 7;
        int l  = (idx >> 3) & 63;
        int ks = (idx >> 9) & 7;
        int f  = idx >> 12;
        int c  = (f << 4) | (l & 15);
        int k  = ks * 32 + ((l >> 4) << 3) + e;
        float s = 0.f;
        #pragma unroll 8
        for (int p = 0; p < 128; ++p) s += qW[k * 128 + p] * kW[c * 128 + p];
        pdst[idx] = (f16)s;
        return;
    }
    if (blockIdx.x != 0) return;       // y == 18: pb
    int c = threadIdx.x;
    float s = 0.f;
    #pragma unroll 8
    for (int p = 0; p < 128; ++p) s += qb[p] * kW[c * 128 + p];
    pb[c] = s;
}

__global__ __launch_bounds__(1024) void scan4_kernel(
    const int* __restrict__ cnt0, int* __restrict__ off0, int N, int NPo)
{
    const int* cnt = cnt0 + (size_t)blockIdx.x * NPo;
    int* off = off0 + (size_t)blockIdx.x * NPo;
    __shared__ int part[1024];
    const int t = threadIdx.x;
    const int chunk = (N + 1023) / 1024;
    const int lo = t * chunk;
    const int hi = min(lo + chunk, N);
    int s = 0;
    for (int i = lo; i < hi; ++i) s += cnt[i];
    part[t] = s;
    __syncthreads();
    for (int d = 1; d < 1024; d <<= 1) {
        int u = (t >= d) ? part[t - d] : 0;
        __syncthreads();
        part[t] += u;
        __syncthreads();
    }
    int running = part[t] - s;
    for (int i = lo; i < hi; ++i) { off[i] = running; running += cnt[i]; }
    if (t == 1023) off[N] = part[1023];
}

// ------------- shared GEMM device pieces -----------------------------------
static __device__ __forceinline__ void stage_A(
    char* smem, const f16* A, const float* A32, int brow, int N, int tid)
{
    #pragma unroll
    for (int j = 0; j < 8; ++j) {
        int i = tid + j * 256;
        int row = i >> 5, slot = i & 31;
        int srow = brow + row; srow = srow < N ? srow : N - 1;
        f16x8 v;
        if (A32) {
            const float* s = &A32[(size_t)srow * 256 + slot * 8];
            float4 v0 = *(const float4*)s;
            float4 v1 = *(const float4*)(s + 4);
            v = f16x8{(f16)v0.x, (f16)v0.y, (f16)v0.z, (f16)v0.w,
                      (f16)v1.x, (f16)v1.y, (f16)v1.z, (f16)v1.w};
        } else {
            v = *(const f16x8*)&A[(size_t)srow * 256 + slot * 8];
        }
        int db = (row * 512 + slot * 16) ^ ((row & 7) << 4);
        *(f16x8*)(smem + db) = v;
    }
}

static __device__ __forceinline__ void gemm_from_lds(
    const char* smem, const f16* W, f32x4 (&acc)[4][4],
    int wave, int lane, int lrow, int kg)
{
    #pragma unroll
    for (int ks = 0; ks < 8; ++ks) {
        f16x8 ah[4], bh[4];
        #pragma unroll
        for (int m = 0; m < 4; ++m) {
            int ab = ((m * 16 + lrow) * 512 + (ks * 4 + kg) * 16) ^ ((lrow & 7) << 4);
            ah[m] = *(const f16x8*)(smem + ab);
        }
        #pragma unroll
        for (int n = 0; n < 4; ++n)
            bh[n] = *(const f16x8*)&W[(size_t)(((wave * 4 + n) * 8 + ks) << 9) + (lane << 3)];
        #pragma unroll
        for (int m = 0; m < 4; ++m)
            #pragma unroll
            for (int n = 0; n < 4; ++n)
                acc[m][n] = __builtin_amdgcn_mfma_f32_16x16x32_f16(
                                ah[m], bh[n], acc[m][n], 0, 0, 0);
    }
}

// GEMM1+relu -> H(LDS, overwrites A region) -> GEMM2; A already staged.
static __device__ __forceinline__ void mlp_from_lds(
    char* smem, const f16* W1, const float* b1, const f16* W2,
    f32x4 (&acc)[4][4], int wave, int lane, int lrow, int kg)
{
    const int wc = wave * 64;
    gemm_from_lds(smem, W1, acc, wave, lane, lrow, kg);
    __syncthreads();
    #pragma unroll
    for (int n = 0; n < 4; ++n) {
        int c = wc + n * 16 + lrow;
        float bv = b1[c];
        #pragma unroll
        for (int m = 0; m < 4; ++m)
            #pragma unroll
            for (int j = 0; j < 4; ++j) {
                int rl = m * 16 + kg * 4 + j;
                float v = fmaxf(acc[m][n][j] + bv, 0.f);
                int hb = (rl * 512 + c * 2) ^ ((rl & 7) << 4);
                *(f16*)(smem + hb) = (f16)v;
            }
    }
    __syncthreads();
    #pragma unroll
    for (int m = 0; m < 4; ++m)
        #pragma unroll
        for (int n = 0; n < 4; ++n)
            acc[m][n] = f32x4{0.f, 0.f, 0.f, 0.f};
    gemm_from_lds(smem, W2, acc, wave, lane, lrow, kg);
}

static __device__ __forceinline__ void fused_mlp_body(
    char* smem, const f16* A, const float* A32,
    const f16* W1, const float* b1, const f16* W2, const float* b2,
    const f16* Ad, f16* Ch, float* Cf, int N, int brow)
{
    const int tid  = threadIdx.x;
    const int wave = tid >> 6, lane = tid & 63;
    const int lrow = lane & 15, kg = lane >> 4;
    const int wc   = wave * 64;

    stage_A(smem, A, A32, brow, N, tid);
    __syncthreads();

    f32x4 acc[4][4] = {};
    mlp_from_lds(smem, W1, b1, W2, acc, wave, lane, lrow, kg);

    #pragma unroll
    for (int n = 0; n < 4; ++n) {
        int c = wc + n * 16 + lrow;
        float bv = b2[c];
        #pragma unroll
        for (int m = 0; m < 4; ++m)
            #pragma unroll
            for (int j = 0; j < 4; ++j) {
                int r = brow + m * 16 + kg * 4 + j;
                if (r >= N) continue;
                size_t o = (size_t)r * 256 + c;
                float v = acc[m][n][j] + bv;
                if (Ad) v += (float)Ad[o];
                if (Cf) Cf[o] = v;
                else    Ch[o] = (f16)v;
            }
    }
}

static __device__ __forceinline__ void gemm1_body(
    char* smem, const float* A32, const f16* W1, const float* b1,
    f16* Ch, int N, int brow)
{
    const int tid  = threadIdx.x;
    const int wave = tid >> 6, lane = tid & 63;
    const int lrow = lane & 15, kg = lane >> 4;
    const int wc   = wave * 64;

    stage_A(smem, nullptr, A32, brow, N, tid);
    __syncthreads();
    f32x4 acc[4][4] = {};
    gemm_from_lds(smem, W1, acc, wave, lane, lrow, kg);

    #pragma unroll
    for (int n = 0; n < 4; ++n) {
        int c = wc + n * 16 + lrow;
        float bv = b1[c];
        #pragma unroll
        for (int m = 0; m < 4; ++m)
            #pragma unroll
            for (int j = 0; j < 4; ++j) {
                int r = brow + m * 16 + kg * 4 + j;
                if (r >= N) continue;
                Ch[(size_t)r * 256 + c] = (f16)(acc[m][n][j] + bv);
            }
    }
}

// ------------- stage2: scatter4 (ILP4) ∥ ft-GEMM ∥ em-MLP ------------------
__global__ __launch_bounds__(256) void stage2_kernel(
    CsrSrc cs, const int* __restrict__ off, int* __restrict__ cur,
    int2* __restrict__ se, int NPo, int Emax,
    const float* __restrict__ features, const float* __restrict__ edge_features,
    const f16* __restrict__ w_ft, const float* __restrict__ ft_b,
    const f16* __restrict__ w_em1, const float* __restrict__ em_b1,
    const f16* __restrict__ w_em2, const float* __restrict__ em_b2,
    f16* __restrict__ F, f16* __restrict__ ef, int N)
{
    __shared__ char smem[32768];
    int y = blockIdx.y;
    if (y < 4) {                       // scatter, 4 edges/thread (ILP)
        int base = blockIdx.x * 1024 + threadIdx.x;
        #pragma unroll
        for (int k = 0; k < 4; ++k) {
            int e = base + k * 256;
            if (e < cs.E[y]) {
                int r = cs.rows[y][e];
                int p = off[(size_t)y * NPo + r] + atomicAdd(&cur[(size_t)y * NPo + r], 1);
                se[(size_t)y * Emax + p] = make_int2(cs.cols[y][e],
                                                     __float_as_int(cs.vals[y][e]));
            }
        }
        return;
    }
    int gx = blockIdx.x;
    if (gx >= (N + 63) / 64) return;
    if (y == 4)
        gemm1_body(smem, features, w_ft, ft_b, F, N, gx * 64);
    else
        fused_mlp_body(smem, nullptr, edge_features, w_em1, em_b1, w_em2, em_b2,
                       nullptr, ef, nullptr, N, gx * 64);
}

// ------------- all 5 SpMM streams in one dispatch (4-way unrolled) ---------
struct Spmm5 {
    const int* off; const int2* se; int NPo; int Emax;
    const f16* F; const f16* ef;
    f16* out[5];   // agg1, aggef, agg2, agg3, agg4
};
__global__ __launch_bounds__(256) void spmm5_kernel(Spmm5 s, int N) {
    int y = blockIdx.y;
    int r = blockIdx.x * 4 + (threadIdx.x >> 6);
    if (r >= N) return;
    int lane = threadIdx.x & 63;
    int a = (y <= 1) ? 0 : y - 1;
    const int* off = s.off + (size_t)a * s.NPo;
    const int2* se = s.se + (size_t)a * s.Emax;
    const f16* X = (y == 1) ? s.ef : s.F;
    f16* Y = s.out[y];
    int e0 = off[r], e1 = off[r + 1];

    float a0 = 0.f, a1 = 0.f, a2 = 0.f, a3 = 0.f;
    int e = e0;
    for (; e + 3 < e1; e += 4) {       // 4 outstanding row gathers
        int2 ev0 = se[e], ev1 = se[e + 1], ev2 = se[e + 2], ev3 = se[e + 3];
        f16x4 x0 = *(const f16x4*)&X[(size_t)ev0.x * DO + lane * 4];
        f16x4 x1 = *(const f16x4*)&X[(size_t)ev1.x * DO + lane * 4];
        f16x4 x2 = *(const f16x4*)&X[(size_t)ev2.x * DO + lane * 4];
        f16x4 x3 = *(const f16x4*)&X[(size_t)ev3.x * DO + lane * 4];
        float v0 = __int_as_float(ev0.y), v1 = __int_as_float(ev1.y);
        float v2 = __int_as_float(ev2.y), v3 = __int_as_float(ev3.y);
        a0 = fmaf(v0, (float)x0[0], a0); a1 = fmaf(v0, (float)x0[1], a1);
        a2 = fmaf(v0, (float)x0[2], a2); a3 = fmaf(v0, (float)x0[3], a3);
        a0 = fmaf(v1, (float)x1[0], a0); a1 = fmaf(v1, (float)x1[1], a1);
        a2 = fmaf(v1, (float)x1[2], a2); a3 = fmaf(v1, (float)x1[3], a3);
        a0 = fmaf(v2, (float)x2[0], a0); a1 = fmaf(v2, (float)x2[1], a1);
        a2 = fmaf(v2, (float)x2[2], a2); a3 = fmaf(v2, (float)x2[3], a3);
        a0 = fmaf(v3, (float)x3[0], a0); a1 = fmaf(v3, (float)x3[1], a1);
        a2 = fmaf(v3, (float)x3[2], a2); a3 = fmaf(v3, (float)x3[3], a3);
    }
    for (; e < e1; ++e) {
        int2 ev = se[e];
        float v = __int_as_float(ev.y);
        f16x4 x = *(const f16x4*)&X[(size_t)ev.x * DO + lane * 4];
        a0 = fmaf(v, (float)x[0], a0); a1 = fmaf(v, (float)x[1], a1);
        a2 = fmaf(v, (float)x[2], a2); a3 = fmaf(v, (float)x[3], a3);
    }
    f16x4 o = {(f16)a0, (f16)a1, (f16)a2, (f16)a3};
    *(f16x4*)&Y[(size_t)r * DO + lane * 4] = o;
}

// ------------- 4 residual MLPs in one dispatch -----------------------------
struct Mlp4 {
    const f16* a[4]; const f16* ad[4];
    const f16* w1[4]; const f16* w2[4];
    const float* b1[4]; const float* b2[4];
    f16* out[4];
};
__global__ __launch_bounds__(256) void mlp4_kernel(Mlp4 p, int N) {
    __shared__ char smem[32768];
    int y = blockIdx.y;
    fused_mlp_body(smem, p.a[y], nullptr, p.w1[y], p.b1[y], p.w2[y], p.b2[y],
                   p.ad[y], p.out[y], nullptr, N, blockIdx.x * 64);
}

// ------------- scores + softmax + combine + final MLP ----------------------
__global__ __launch_bounds__(256) void score_combine_mlp_kernel(
    const f16* __restrict__ F, const f16* __restrict__ P,
    const float* __restrict__ pb,
    const f16* __restrict__ F1, const f16* __restrict__ F2,
    const f16* __restrict__ F3, const f16* __restrict__ F4,
    const f16* __restrict__ mW1, const float* __restrict__ mb1,
    const f16* __restrict__ mW2, const float* __restrict__ mb2,
    float* __restrict__ Out, int N)
{
    __shared__ char smem[32768];
    __shared__ float sred[4][64][5];
    __shared__ float w5[64][5];

    const int tid  = threadIdx.x;
    const int wave = tid >> 6, lane = tid & 63;
    const int lrow = lane & 15, kg = lane >> 4;
    const int wc   = wave * 64;
    const int brow = blockIdx.x * 64;

    stage_A(smem, F, nullptr, brow, N, tid);
    __syncthreads();

    f32x4 acc[4][4] = {};
    gemm_from_lds(smem, P, acc, wave, lane, lrow, kg);

    #pragma unroll
    for (int m = 0; m < 4; ++m) {
        #pragma unroll
        for (int j = 0; j < 4; ++j) {
            int rl = m * 16 + kg * 4 + j;
            int r  = brow + rl;
            float p0 = 0.f, p1 = 0.f, p2 = 0.f, p3 = 0.f, p4 = 0.f;
            if (r < N) {
                #pragma unroll
                for (int n = 0; n < 4; ++n) {
                    int c = wc + n * 16 + lrow;
                    float v = acc[m][n][j] + pb[c];
                    int ab = (rl * 512 + c * 2) ^ ((rl & 7) << 4);
                    float f0 = (float)*(const f16*)(smem + ab);
                    size_t fo = (size_t)r * 256 + c;
                    p0 += v * f0;
                    p1 += v * (float)F1[fo];
                    p2 += v * (float)F2[fo];
                    p3 += v * (float)F3[fo];
                    p4 += v * (float)F4[fo];
                }
            }
            #pragma unroll
            for (int d = 1; d < 16; d <<= 1) {
                p0 += __shfl_xor(p0, d, 64);
                p1 += __shfl_xor(p1, d, 64);
                p2 += __shfl_xor(p2, d, 64);
                p3 += __shfl_xor(p3, d, 64);
                p4 += __shfl_xor(p4, d, 64);
            }
            if (lrow == 0) {
                sred[wave][rl][0] = p0; sred[wave][rl][1] = p1;
                sred[wave][rl][2] = p2; sred[wave][rl][3] = p3;
                sred[wave][rl][4] = p4;
            }
        }
    }
    __syncthreads();

    if (tid < 64) {
        float s[5];
        #pragma unroll
        for (int k = 0; k < 5; ++k)
            s[k] = sred[0][tid][k] + sred[1][tid][k] + sred[2][tid][k] + sred[3][tid][k];
        float mx = fmaxf(fmaxf(fmaxf(s[0], s[1]), fmaxf(s[2], s[3])), s[4]);
        float sum = 0.f;
        #pragma unroll
        for (int k = 0; k < 5; ++k) { s[k] = expf(s[k] - mx); sum += s[k]; }
        float inv = 1.f / sum;
        #pragma unroll
        for (int k = 0; k < 5; ++k) w5[tid][k] = s[k] * inv;
    }
    __syncthreads();

    #pragma unroll
    for (int m = 0; m < 4; ++m) {
        #pragma unroll
        for (int j = 0; j < 4; ++j) {
            int rl = m * 16 + kg * 4 + j;
            int r  = brow + rl;
            float w0 = w5[rl][0], w1 = w5[rl][1], w2 = w5[rl][2],
                  w3 = w5[rl][3], w4 = w5[rl][4];
            #pragma unroll
            for (int n = 0; n < 4; ++n) {
                int c = wc + n * 16 + lrow;
                int ab = (rl * 512 + c * 2) ^ ((rl & 7) << 4);
                float f0 = (float)*(const f16*)(smem + ab);
                float res = f0;
                if (r < N) {
                    size_t fo = (size_t)r * 256 + c;
                    res = w0 * f0
                        + w1 * (float)F1[fo]
                        + w2 * (float)F2[fo]
                        + w3 * (float)F3[fo]
                        + w4 * (float)F4[fo];
                }
                *(f16*)(smem + ab) = (f16)res;
            }
        }
    }
    __syncthreads();

    #pragma unroll
    for (int m = 0; m < 4; ++m)
        #pragma unroll
        for (int n = 0; n < 4; ++n)
            acc[m][n] = f32x4{0.f, 0.f, 0.f, 0.f};
    mlp_from_lds(smem, mW1, mb1, mW2, acc, wave, lane, lrow, kg);

    #pragma unroll
    for (int n = 0; n < 4; ++n) {
        int c = wc + n * 16 + lrow;
        float bv = mb2[c];
        #pragma unroll
        for (int m = 0; m < 4; ++m)
            #pragma unroll
            for (int j = 0; j < 4; ++j) {
                int r = brow + m * 16 + kg * 4 + j;
                if (r >= N) continue;
                Out[(size_t)r * 256 + c] = acc[m][n][j] + bv;
            }
    }
}

extern "C" void kernel_launch(void* const* d_in, const int* in_sizes, int n_in,
                              void* d_out, int out_size, void* d_ws, size_t ws_size,
                              hipStream_t stream)
{
    const float* features      = (const float*)d_in[0];
    const float* edge_features = (const float*)d_in[1];
    CsrSrc cs;
    for (int i = 0; i < 4; ++i) {
        const int* idx = (const int*)d_in[2 + 2 * i];
        cs.E[i]    = in_sizes[3 + 2 * i];
        cs.rows[i] = idx;
        cs.cols[i] = idx + cs.E[i];
        cs.vals[i] = (const float*)d_in[3 + 2 * i];
    }
    const int Emax = max(max(cs.E[0], cs.E[1]), max(cs.E[2], cs.E[3]));

    const float* ft_W = (const float*)d_in[10]; const float* ft_b = (const float*)d_in[11];
    const float* fo_W1 = (const float*)d_in[12]; const float* fo_b1 = (const float*)d_in[13];
    const float* fo_W2 = (const float*)d_in[14]; const float* fo_b2 = (const float*)d_in[15];
    const float* em_W1 = (const float*)d_in[16]; const float* em_b1 = (const float*)d_in[17];
    const float* em_W2 = (const float*)d_in[18]; const float* em_b2 = (const float*)d_in[19];
    const float* so_W1 = (const float*)d_in[20]; const float* so_b1 = (const float*)d_in[21];
    const float* so_W2 = (const float*)d_in[22]; const float* so_b2 = (const float*)d_in[23];
    const float* to_W1 = (const float*)d_in[24]; const float* to_b1 = (const float*)d_in[25];
    const float* to_W2 = (const float*)d_in[26]; const float* to_b2 = (const float*)d_in[27];
    const float* qo_W1 = (const float*)d_in[28]; const float* qo_b1 = (const float*)d_in[29];
    const float* qo_W2 = (const float*)d_in[30]; const float* qo_b2 = (const float*)d_in[31];
    const float* m_W1  = (const float*)d_in[32]; const float* m_b1  = (const float*)d_in[33];
    const float* m_W2  = (const float*)d_in[34]; const float* m_b2  = (const float*)d_in[35];
    const float* q_W   = (const float*)d_in[36]; const float* q_b   = (const float*)d_in[37];
    const float* k_W   = (const float*)d_in[38]; const float* k_b   = (const float*)d_in[39];
    (void)k_b;   // q.k_b constant across the 5 scores -> softmax-invariant

    const int N = in_sizes[0] / 256;
    const size_t NS = (size_t)N * DO;

    // ---- workspace: CSR(4, packed) + 7 fp16 slots + packed WT -------------
    char* base = (char*)d_ws;
    size_t o = 0;
    auto take = [&](size_t bytes) { char* p = base + o; o += (bytes + 63) & ~(size_t)63; return p; };
    const int NPo = (N + 64) & ~63;
    int*  cnt = (int*)take((size_t)4 * NPo * 4);
    int*  cur = (int*)take((size_t)4 * NPo * 4);   // contiguous with cnt
    int*  off = (int*)take((size_t)4 * NPo * 4);
    int2* se  = (int2*)take((size_t)4 * Emax * 8);
    f16* B1 = (f16*)take(NS * 2);      // agg1 -> fo
    f16* B2 = (f16*)take(NS * 2);      // aggef
    f16* B3 = (f16*)take(NS * 2);      // ef
    f16* B4 = (f16*)take(NS * 2);      // F
    f16* B5 = (f16*)take(NS * 2);      // agg2 -> so
    f16* B6 = (f16*)take(NS * 2);      // agg3 -> to
    f16* B7 = (f16*)take(NS * 2);      // agg4 -> qo
    const size_t WSQ = 65536;
    f16* WT = (f16*)take(14 * WSQ * 2);    // 13 weights + P (slot 13), packed
    float* pb = (float*)take(256 * 4);
    if (o > ws_size) return;           // graceful guard

    f16* F = B4;

    f16* w[14];
    for (int i = 0; i < 14; ++i) w[i] = WT + (size_t)i * WSQ;

    dim3 blk(256);
    const int EG4 = (Emax + 1023) / 1024;
    const int GG  = (N + 63) / 64;
    const int PX  = (EG4 > 256) ? EG4 : 256;
    const int SX  = (EG4 > GG) ? EG4 : GG;

    // 0. zero cnt+cur (contiguous)
    hipMemsetAsync(cnt, 0, (size_t)8 * NPo * 4, stream);

    // 1. prep: count4(ILP4) ∥ transpose13 ∥ build_P ∥ build_pb
    {
        WPack wp;
        const float* src[13] = {ft_W, fo_W1, fo_W2, em_W1, em_W2, so_W1, so_W2,
                                to_W1, to_W2, qo_W1, qo_W2, m_W1, m_W2};
        for (int i = 0; i < 13; ++i) { wp.w[i].src = src[i]; wp.w[i].dst = w[i]; }
        hipLaunchKernelGGL(prep_kernel, dim3(PX, 19), blk, 0, stream,
                           cs, cnt, NPo, wp, q_W, k_W, q_b, w[13], pb);
    }
    // 2. scan4
    hipLaunchKernelGGL(scan4_kernel, dim3(4), dim3(1024), 0, stream, cnt, off, N, NPo);
    // 3. stage2: scatter4(ILP4) ∥ ft-GEMM ∥ em-MLP
    hipLaunchKernelGGL(stage2_kernel, dim3(SX, 6), blk, 0, stream,
                       cs, off, cur, se, NPo, Emax,
                       features, edge_features,
                       w[0], ft_b, w[3], em_b1, w[4], em_b2, F, B3, N);
    // 4. all 5 spmm streams: agg1->B1, aggef->B2, agg2->B5, agg3->B6, agg4->B7
    {
        Spmm5 sp;
        sp.off = off; sp.se = se; sp.NPo = NPo; sp.Emax = Emax;
        sp.F = F; sp.ef = B3;
        sp.out[0] = B1; sp.out[1] = B2; sp.out[2] = B5; sp.out[3] = B6; sp.out[4] = B7;
        hipLaunchKernelGGL(spmm5_kernel, dim3((N + 3) / 4, 5), blk, 0, stream, sp, N);
    }
    // 5. fo/so/to/qo MLPs in one dispatch
    {
        Mlp4 p;
        const f16* a[4]  = {B1, B5, B6, B7};
        const f16* ad[4] = {B2, B5, B6, B7};
        f16* out[4]      = {B1, B5, B6, B7};
        int wi1[4] = {1, 5, 7, 9}, wi2[4] = {2, 6, 8, 10};
        const float* bb1[4] = {fo_b1, so_b1, to_b1, qo_b1};
        const float* bb2[4] = {fo_b2, so_b2, to_b2, qo_b2};
        for (int i = 0; i < 4; ++i) {
            p.a[i] = a[i]; p.ad[i] = ad[i]; p.out[i] = out[i];
            p.w1[i] = w[wi1[i]]; p.w2[i] = w[wi2[i]];
            p.b1[i] = bb1[i]; p.b2[i] = bb2[i];
        }
        hipLaunchKernelGGL(mlp4_kernel, dim3(GG, 4), blk, 0, stream, p, N);
    }
    // 6. scores + softmax + combine + final MLP -> f32 d_out (write-only)
    hipLaunchKernelGGL(score_combine_mlp_kernel, dim3(GG), blk, 0, stream,
                       F, w[13], pb, B1, B5, B6, B7,
                       w[11], m_b1, w[12], m_b2, (float*)d_out, N);
}